// Round 22
// baseline (115.098 us; speedup 1.0000x reference)
//
#include <hip/hip_runtime.h>
#include <math.h>

#define F_FILT   40
#define K_GABOR  401
#define HOP      160
#define T_LEN    160000
#define B_BATCH  8
#define EPS_PCENF 1e-6f
#define EPS_INF   1e-5f

// ---- kernel1 (MFMA conv, all 5 groups per block) geometry ----
#define NG       5
#define GF       8
#define NCHK     13          // absolute 32-tap chunks covering taps 0..415
#define TC2      256         // time samples per block (4 waves x 4 jtiles x 16)
#define UW2      4
#define NCH2     625         // T_LEN / TC2
#define NSTG2    84          // staging slots (84 x 8 samples = 672)
#define PHS2     356         // phase array stride in words (89 uint4; mod32=4)

// ---- kernel2 (PCEN, barrier-free per-wave, 1280-sample tiles) ----
#define PC_THREADS 256
#define PC_NWAVES  4
#define SPAN     6400
#define W_NT     5
#define NSP      25
#define RT       20
#define KP       208
#define HALOP    200
#define RINGW    840
#define WSTR     1048

typedef _Float16 h2_t  __attribute__((ext_vector_type(2)));
typedef _Float16 half8 __attribute__((ext_vector_type(8)));
typedef float    f32x4 __attribute__((ext_vector_type(4)));

__device__ __forceinline__ float fdot2(h2_t a, h2_t b, float c) {
    return __builtin_amdgcn_fdot2(a, b, c, false);
}
__device__ __forceinline__ unsigned pk2(float a, float b) {
    return __builtin_bit_cast(unsigned, __builtin_amdgcn_cvt_pkrtz(a, b));
}
__device__ __forceinline__ h2_t bch(unsigned u) {
    return __builtin_bit_cast(h2_t, u);
}
__device__ __forceinline__ float fexp2(float x) { return __builtin_amdgcn_exp2f(x); }
__device__ __forceinline__ float flog2(float x) { return __builtin_amdgcn_logf(x); }

// group truncation params; 4.0 sigma; klo 32-aligned
__device__ __forceinline__ void group_span(float sigma0, int& klo, int& nk) {
    const int R = min(200, (int)ceilf(4.0f * sigma0));
    klo = (200 - R) & ~31;
    nk  = ((200 + R - klo) >> 5) + 1;
    if (nk > NCHK) nk = NCHK;
}

// ---------- setup: A-table (absolute chunks: 52 x 16 rows x 8 taps per group) ----------
__global__ __launch_bounds__(256) void leaf_weights(
    const float* __restrict__ eta_g, const float* __restrict__ sigma_g,
    const float* __restrict__ bw_g,
    _Float16* __restrict__ Atab, unsigned* __restrict__ pktab)
{
    const int gi = blockIdx.x;
    const int f0 = gi * GF;

    // A: 52 chunks x 16 rows x 8 taps, ABSOLUTE tap index (k = 8*c8 + i)
    for (int idx = threadIdx.x; idx < 52 * 16 * 8; idx += 256) {
        const int c8 = idx >> 7;
        const int m  = (idx >> 3) & 15;
        const int i  = idx & 7;
        const int f  = f0 + (m >> 1);
        const int k  = c8 * 8 + i;
        float w = 0.f;
        if (k <= 400) {
            const float sg = sigma_g[f];
            const float t  = (float)(k - 200);
            const float z  = t / sg;
            const float e  = (0.3989422804014327f / sg) * expf(-0.5f * z * z);
            const float ph = eta_g[f] * t;
            w = (m & 1) ? e * sinf(ph) : e * cosf(ph);
        }
        Atab[(size_t)(gi * 52 + c8) * 128 + m * 8 + i] = (_Float16)w;
    }
    // pool kernel for this group's 8 filters
    for (int idx = threadIdx.x; idx < GF * KP; idx += 256) {
        const int fl = idx / KP, i = idx % KP;
        const int f = f0 + fl;
        const float bw  = fminf(fmaxf(bw_g[f], 2.0f / 401.0f), 0.5f);
        const float den = bw * 0.5f * 400.0f;
        float pp[2];
        for (int j = 0; j < 2; ++j) {
            int k = 2 * i + j;
            float pv = 0.f;
            if (k < K_GABOR) {
                float tp = (float)(k - 201);
                float d = tp / den;
                pv = expf(-0.5f * d * d);
            }
            pp[j] = pv;
        }
        pktab[f * KP + i] = pk2(pp[0], pp[1]);
    }
}

// ---------- kernel1: MFMA Gabor conv, all 5 groups share B fragments ----------
__global__ __launch_bounds__(256) void leaf_conv(
    const float* __restrict__ x,
    const float* __restrict__ sigma_g,
    const _Float16* __restrict__ Atab,
    _Float16* __restrict__ Pall)           // [8][40][160000] f16
{
    __shared__ unsigned ph[8 * PHS2];      // 8 phase-shifted fragment arrays

    const int ch = blockIdx.x % NCH2;
    const int b  = blockIdx.x / NCH2;
    const int tid = threadIdx.x;
    const int lane = tid & 63;
    const int w    = tid >> 6;

    const float* __restrict__ xb = x + (size_t)b * T_LEN;
    _Float16* __restrict__ Pb = Pall + (size_t)b * F_FILT * T_LEN;

    const int t0   = ch * TC2;
    const int base = t0 - 400;

    // per-group activity windows (wave-uniform scalars)
    int c0g[NG], c1g[NG];
#pragma unroll
    for (int gi = 0; gi < NG; ++gi) {
        int klo, nk;
        group_span(sigma_g[gi * GF], klo, nk);
        c0g[gi] = klo >> 5;
        c1g[gi] = (klo >> 5) + nk;
    }

    // ---- stage x: 8 phase-shifted 16B fragments per 8-sample slot ----
    if (tid < NSTG2) {
        const int g0 = base + 8 * tid;
        float v[15];
        if (g0 >= 0 && g0 + 14 < T_LEN) {
            const float4 a0 = *(const float4*)(xb + g0);
            const float4 a1 = *(const float4*)(xb + g0 + 4);
            const float4 a2 = *(const float4*)(xb + g0 + 8);
            const float4 a3 = *(const float4*)(xb + g0 + 12);
            v[0]=a0.x; v[1]=a0.y; v[2]=a0.z; v[3]=a0.w;
            v[4]=a1.x; v[5]=a1.y; v[6]=a1.z; v[7]=a1.w;
            v[8]=a2.x; v[9]=a2.y; v[10]=a2.z; v[11]=a2.w;
            v[12]=a3.x; v[13]=a3.y; v[14]=a3.z;
        } else {
#pragma unroll
            for (int e = 0; e < 15; ++e) {
                const int gidx = g0 + e;
                v[e] = (gidx >= 0 && gidx < T_LEN) ? xb[gidx] : 0.f;
            }
        }
        unsigned pw[14];
#pragma unroll
        for (int s = 0; s < 14; ++s) pw[s] = pk2(v[s], v[s + 1]);
#pragma unroll
        for (int r = 0; r < 8; ++r) {
            uint4 fr;
            fr.x = pw[r]; fr.y = pw[r + 2]; fr.z = pw[r + 4]; fr.w = pw[r + 6];
            *(uint4*)&ph[r * PHS2 + 4 * tid] = fr;
        }
    }
    __syncthreads();

    // ---- k-loop: 13 absolute chunks, shared B fragments, 5 groups ----
    const int n  = lane & 15;
    const int kb = lane >> 4;
    const int q  = n + 8 * kb + 64 * w;                  // fragment start sample
    const int pbase = (q & 7) * (PHS2 / 4) + (q >> 3);   // uint4 idx; +2u +4jk

    f32x4 acc[NG][UW2];
#pragma unroll
    for (int gi = 0; gi < NG; ++gi)
#pragma unroll
        for (int u = 0; u < UW2; ++u) acc[gi][u] = (f32x4){0.f, 0.f, 0.f, 0.f};

    const uint4* ph4 = (const uint4*)ph;
    const uint4* Ap  = (const uint4*)Atab;

    uint4 F[UW2];
#pragma unroll
    for (int u = 0; u < UW2; ++u) F[u] = ph4[pbase + 2 * u];

    uint4 aC[NG], aN[NG];
#pragma unroll
    for (int gi = 0; gi < NG; ++gi) aC[gi] = Ap[(gi * 52 + kb) * 16 + n];

#pragma unroll
    for (int jk = 0; jk < NCHK; ++jk) {
        if (jk + 1 < NCHK) {
#pragma unroll
            for (int gi = 0; gi < NG; ++gi)
                aN[gi] = Ap[(gi * 52 + 4 * (jk + 1) + kb) * 16 + n];
        }
#pragma unroll
        for (int gi = 0; gi < NG; ++gi) {
            if (jk >= c0g[gi] && jk < c1g[gi]) {
                const half8 aCur = __builtin_bit_cast(half8, aC[gi]);
#pragma unroll
                for (int u = 0; u < UW2; ++u) {
                    acc[gi][u] = __builtin_amdgcn_mfma_f32_16x16x32_f16(
                        aCur, __builtin_bit_cast(half8, F[(2 * jk + u) & 3]),
                        acc[gi][u], 0, 0, 0);
                }
            }
        }
        if (jk + 1 < NCHK) {
            F[(2 * (jk + 1) + 2) & 3] = ph4[pbase + 4 * (jk + 1) + 4];
            F[(2 * (jk + 1) + 3) & 3] = ph4[pbase + 4 * (jk + 1) + 6];
#pragma unroll
            for (int gi = 0; gi < NG; ++gi) aC[gi] = aN[gi];
        }
    }

    // ---- epilogue: power, store P for all 5 groups ----
    const int g = lane >> 4;
#pragma unroll
    for (int gi = 0; gi < NG; ++gi) {
        const int fA = gi * GF + 2 * g;
#pragma unroll
        for (int u = 0; u < UW2; ++u) {
            const int t = t0 + (w * UW2 + u) * 16 + n;
            const float P0 = acc[gi][u].x * acc[gi][u].x + acc[gi][u].y * acc[gi][u].y;
            const float P1 = acc[gi][u].z * acc[gi][u].z + acc[gi][u].w * acc[gi][u].w;
            Pb[(size_t)fA * T_LEN + t]       = (_Float16)P0;
            Pb[(size_t)(fA + 1) * T_LEN + t] = (_Float16)P1;
        }
    }
}

// ---------- kernel2: EMA + PCEN + pooling, barrier-free (one wave = one span) ----------
__global__ __launch_bounds__(PC_THREADS) void leaf_pcen(
    const _Float16* __restrict__ Pall,
    const float* __restrict__ bias_g,
    const float* __restrict__ ema_g,
    const float* __restrict__ alpha_g,
    const float* __restrict__ delta_g,
    const float* __restrict__ root_g,
    const unsigned* __restrict__ pktab,
    float* __restrict__ outp)
{
    __shared__ unsigned lds[PC_NWAVES * WSTR];

    const int tid  = threadIdx.x;
    const int lane = tid & 63;
    const int wv   = tid >> 6;
    const int wid  = blockIdx.x * PC_NWAVES + wv;   // 0..7999
    const int sp   = wid % NSP;
    const int bf   = wid / NSP;
    const int f    = bf % F_FILT;

    unsigned* ring = lds + wv * WSTR;        // [0,200) halo | [200,840) tile
    unsigned* pkl  = ring + RINGW;           // pool kernel, 208 words

    const float sw    = fminf(fmaxf(ema_g[f], 0.0f), 1.0f);
    const float a     = 1.0f - sw;
    const float alpha = fminf(alpha_g[f], 1.0f);
    const float inv_r = 1.0f / fmaxf(root_g[f], 1.0f);
    const float dlt   = delta_g[f];
    const float dpow  = fexp2(inv_r * flog2(dlt));
    const bool  rt1   = (inv_r == 1.0f);     // (q+d)^1 - d^1 == p*denp
    const float bias  = bias_g[f];

    for (int i = lane; i < KP; i += 64) pkl[i] = pktab[f * KP + i];
    for (int i = lane; i < HALOP; i += 64) ring[i] = 0u;

    // scan factors: A1 = a^RT (a^20); A64 = per-tile decay a^1280
    const float a2 = a * a, a4 = a2 * a2, a8 = a4 * a4, a16 = a8 * a8;
    const float A1  = a16 * a4;          // a^20
    const float A2  = A1 * A1, A4 = A2 * A2, A8 = A4 * A4;
    const float A16 = A8 * A8, A32 = A16 * A16, A64 = A32 * A32;
    float Al = 1.0f;
    if (lane & 1)  Al *= A1;
    if (lane & 2)  Al *= A2;
    if (lane & 4)  Al *= A4;
    if (lane & 8)  Al *= A8;
    if (lane & 16) Al *= A16;
    if (lane & 32) Al *= A32;

    const unsigned* PU = (const unsigned*)(Pall + (size_t)bf * T_LEN);
    const int wbase = sp * (SPAN / 2);       // word base of this span
    const int itStart = (sp == 0) ? 0 : -1;  // warm-up tile for sp>0
    float carry = 0.f;

    unsigned sv[10];
    {
        const int tb = wbase + itStart * 640 + lane * 10;
#pragma unroll
        for (int q = 0; q < 10; ++q) sv[q] = PU[tb + q];
    }

    for (int it = itStart; it < W_NT; ++it) {
        // unpack powers
        float p[RT];
#pragma unroll
        for (int q = 0; q < 10; ++q) {
            const h2_t hh = bch(sv[q]);
            p[2 * q]     = (float)hh.x;
            p[2 * q + 1] = (float)hh.y;
        }
        // prefetch next tile
        {
            const int nt = it + 1;
            const int tb = wbase + (nt < W_NT ? nt : 0) * 640 + lane * 10;
#pragma unroll
            for (int q = 0; q < 10; ++q) sv[q] = PU[tb + q];
        }

        float up[RT];
        float uu = 0.f;
#pragma unroll
        for (int r = 0; r < RT; ++r) {
            uu = fmaf(a, uu, sw * p[r]);
            up[r] = uu;
        }

        float cc = carry;
        if (sp == 0 && it == 0) cc = __shfl(p[0], 0);   // ema[0] = p[0] (a+sw=1)

        // intra-wave Kogge-Stone scan
        float v = uu;
        {
            float tv;
            tv = __shfl_up(v, 1);  if (lane >= 1)  v = fmaf(A1,  tv, v);
            tv = __shfl_up(v, 2);  if (lane >= 2)  v = fmaf(A2,  tv, v);
            tv = __shfl_up(v, 4);  if (lane >= 4)  v = fmaf(A4,  tv, v);
            tv = __shfl_up(v, 8);  if (lane >= 8)  v = fmaf(A8,  tv, v);
            tv = __shfl_up(v, 16); if (lane >= 16) v = fmaf(A16, tv, v);
            tv = __shfl_up(v, 32); if (lane >= 32) v = fmaf(A32, tv, v);
        }
        const float vlast = __shfl(v, 63);
        float cin;
        {
            float ve = __shfl_up(v, 1);
            if (lane == 0) ve = 0.f;
            cin = fmaf(Al, cc, ve);
        }
        carry = fmaf(A64, cc, vlast);

        // PCEN + f16 ring writes (own wave region only)
        float apr = a;
#pragma unroll
        for (int j = 0; j < 10; ++j) {
            const float e0 = fmaf(apr, cin, up[2 * j]);     apr *= a;
            const float e1 = fmaf(apr, cin, up[2 * j + 1]); apr *= a;
            const float d0 = fexp2(-alpha * flog2(EPS_PCENF + e0));
            const float d1 = fexp2(-alpha * flog2(EPS_PCENF + e1));
            float c0, c1;
            if (rt1) {
                c0 = p[2 * j] * d0;
                c1 = p[2 * j + 1] * d1;
            } else {
                const float q0 = fmaf(p[2 * j],     d0, dlt);
                const float q1 = fmaf(p[2 * j + 1], d1, dlt);
                c0 = fexp2(inv_r * flog2(q0)) - dpow;
                c1 = fexp2(inv_r * flog2(q1)) - dpow;
            }
            ring[HALOP + lane * 10 + j] = pk2(c0, c1);
        }

        // pooling: 8 outputs x 8 lanes, direct global write
        if (it >= 0) {
            const int o = lane >> 3, l = lane & 7;
            float part = 0.f;
#pragma unroll
            for (int t = 0; t < 26; ++t) {
                const int kpp = l + 8 * t;    // 0..207
                part = fdot2(bch(ring[o * 80 + kpp]), bch(pkl[kpp]), part);
            }
            part += __shfl_xor(part, 1, 8);
            part += __shfl_xor(part, 2, 8);
            part += __shfl_xor(part, 4, 8);
            if (l == 0)
                outp[(size_t)bf * 1000 + sp * (W_NT * 8) + it * 8 + o] = part + bias;
        }

        // slide halo: 200 words = 50 uint4 (read [640,840) -> write [0,200))
        if (lane < 50) {
            const uint4 hv = *(const uint4*)&ring[640 + 4 * lane];
            *(uint4*)&ring[4 * lane] = hv;
        }
    }
}

// ---------- instance norm over 1000 frames, in place ----------
__global__ __launch_bounds__(256) void leaf_norm(float* __restrict__ out)
{
    const int bf = blockIdx.x;
    float* p = out + (size_t)bf * 1000;
    __shared__ float buf[1000];
    __shared__ float red[4];
    const int tid = threadIdx.x;
    const int lane = tid & 63, wave = tid >> 6;

    float sum = 0.0f;
    for (int i = tid; i < 1000; i += 256) { float v = p[i]; buf[i] = v; sum += v; }
    for (int m = 1; m < 64; m <<= 1) sum += __shfl_xor(sum, m);
    if (lane == 0) red[wave] = sum;
    __syncthreads();
    const float mean = (red[0] + red[1] + red[2] + red[3]) * 0.001f;

    float vs = 0.0f;
    for (int i = tid; i < 1000; i += 256) { float d = buf[i] - mean; vs += d * d; }
    for (int m = 1; m < 64; m <<= 1) vs += __shfl_xor(vs, m);
    __syncthreads();
    if (lane == 0) red[wave] = vs;
    __syncthreads();
    const float var   = (red[0] + red[1] + red[2] + red[3]) * 0.001f;
    const float scale = rsqrtf(var + EPS_INF);
    for (int i = tid; i < 1000; i += 256) p[i] = (buf[i] - mean) * scale;
}

extern "C" void kernel_launch(void* const* d_in, const int* in_sizes, int n_in,
                              void* d_out, int out_size, void* d_ws, size_t ws_size,
                              hipStream_t stream)
{
    const float* x     = (const float*)d_in[0];
    const float* eta   = (const float*)d_in[1];
    const float* sigma = (const float*)d_in[2];
    const float* bw    = (const float*)d_in[3];
    const float* bias  = (const float*)d_in[4];
    const float* emaw  = (const float*)d_in[5];
    const float* alpha = (const float*)d_in[6];
    const float* delta = (const float*)d_in[7];
    const float* root  = (const float*)d_in[8];
    float* outp = (float*)d_out;

    _Float16* Atab  = (_Float16*)d_ws;                       // 133,120 B
    unsigned* pktab = (unsigned*)((char*)d_ws + 133120);     // 33,280 B
    _Float16* Pall  = (_Float16*)((char*)d_ws + 166400);     // 8*40*160000*2 = 102.4 MB

    hipLaunchKernelGGL(leaf_weights, dim3(NG), dim3(256), 0, stream,
                       eta, sigma, bw, Atab, pktab);
    hipLaunchKernelGGL(leaf_conv, dim3(B_BATCH * NCH2), dim3(256), 0, stream,
                       x, sigma, Atab, Pall);
    hipLaunchKernelGGL(leaf_pcen, dim3(B_BATCH * F_FILT * NSP / PC_NWAVES), dim3(PC_THREADS),
                       0, stream, Pall, bias, emaw, alpha, delta, root, pktab, outp);
    hipLaunchKernelGGL(leaf_norm, dim3(B_BATCH * F_FILT), dim3(256), 0, stream, outp);
}

// Round 23
// 101.830 us; speedup vs baseline: 1.1303x; 1.1303x over previous
//
#include <hip/hip_runtime.h>
#include <math.h>

#define F_FILT   40
#define K_GABOR  401
#define HOP      160
#define T_LEN    160000
#define B_BATCH  8
#define EPS_PCENF 1e-6f
#define EPS_INF   1e-5f

// ---- kernel1 (MFMA conv) geometry ----
#define NG       5           // filter groups of 8
#define GF       8
#define NKMAX    13          // max K chunks of 32 taps (416)
#define TC       640         // time samples per block (4 waves x 10 jtiles x 16)
#define UW       10          // j-tiles per wave
#define NCH1     250         // T_LEN / TC
#define NSTG     136         // staging threads (136 slots x 8 samples)
#define PHS      548         // phase array stride in words (137 uint4; mod32=4)

// ---- kernel2 (PCEN, barrier-free per-wave, 1280-sample tiles) ----
#define PC_THREADS 256
#define PC_NWAVES  4
#define SPAN     6400        // samples per wave span
#define W_NT     5           // payload tiles per span (1280 samples each)
#define NSP      25          // spans per (b,f) = T_LEN/SPAN
#define RT       20          // samples per lane per tile
#define KP       208
#define HALOP    200
#define RINGW    840         // 200 halo + 640 tile pair-words
#define WSTR     1048        // per-wave LDS words (ring + pk)

typedef _Float16 h2_t  __attribute__((ext_vector_type(2)));
typedef _Float16 half8 __attribute__((ext_vector_type(8)));
typedef float    f32x4 __attribute__((ext_vector_type(4)));

__device__ __forceinline__ float fdot2(h2_t a, h2_t b, float c) {
    return __builtin_amdgcn_fdot2(a, b, c, false);
}
__device__ __forceinline__ unsigned pk2(float a, float b) {
    return __builtin_bit_cast(unsigned, __builtin_amdgcn_cvt_pkrtz(a, b));
}
__device__ __forceinline__ h2_t bch(unsigned u) {
    return __builtin_bit_cast(h2_t, u);
}
// hardware transcendentals: v_exp_f32 (2^x), v_log_f32 (log2 x), ~1 ULP
__device__ __forceinline__ float fexp2(float x) { return __builtin_amdgcn_exp2f(x); }
__device__ __forceinline__ float flog2(float x) { return __builtin_amdgcn_logf(x); }

// group truncation params (shared formula: leaf_weights & k1); 4.0 sigma
__device__ __forceinline__ void group_span(float sigma0, int& klo, int& nk) {
    const int R = min(200, (int)ceilf(4.0f * sigma0));
    klo = (200 - R) & ~31;
    nk  = ((200 + R - klo) >> 5) + 1;
    if (nk > NKMAX) nk = NKMAX;
}

// ---------- setup: A-table (16 rows x 416 taps f16 per group) + pool kernel ----------
__global__ __launch_bounds__(256) void leaf_weights(
    const float* __restrict__ eta_g, const float* __restrict__ sigma_g,
    const float* __restrict__ bw_g,
    _Float16* __restrict__ Atab, unsigned* __restrict__ pktab)
{
    const int gi = blockIdx.x;
    const int f0 = gi * GF;
    int klo, nk;
    group_span(sigma_g[f0], klo, nk);

    // A: 52 chunks x 16 rows x 8 taps
    for (int idx = threadIdx.x; idx < 52 * 16 * 8; idx += 256) {
        const int c8 = idx >> 7;
        const int m  = (idx >> 3) & 15;
        const int i  = idx & 7;
        const int f  = f0 + (m >> 1);
        const int k  = klo + c8 * 8 + i;
        float w = 0.f;
        if (k <= 400) {
            const float sg = sigma_g[f];
            const float t  = (float)(k - 200);
            const float z  = t / sg;
            const float e  = (0.3989422804014327f / sg) * expf(-0.5f * z * z);
            const float ph = eta_g[f] * t;
            w = (m & 1) ? e * sinf(ph) : e * cosf(ph);
        }
        Atab[(size_t)(gi * 52 + c8) * 128 + m * 8 + i] = (_Float16)w;
    }
    // pool kernel for this group's 8 filters
    for (int idx = threadIdx.x; idx < GF * KP; idx += 256) {
        const int fl = idx / KP, i = idx % KP;
        const int f = f0 + fl;
        const float bw  = fminf(fmaxf(bw_g[f], 2.0f / 401.0f), 0.5f);
        const float den = bw * 0.5f * 400.0f;
        float pp[2];
        for (int j = 0; j < 2; ++j) {
            int k = 2 * i + j;
            float pv = 0.f;
            if (k < K_GABOR) {
                float tp = (float)(k - 201);
                float d = tp / den;
                pv = expf(-0.5f * d * d);
            }
            pp[j] = pv;
        }
        pktab[f * KP + i] = pk2(pp[0], pp[1]);
    }
}

// fully-unrolled k-loop, circular fragment file; 1 ds_read_b128 per fragment
template<int NK>
__device__ __forceinline__ void conv_kloop(
    const uint4* __restrict__ ph4, const uint4* __restrict__ Ap,
    int aBase, int pbase, f32x4* acc)
{
    uint4 F[UW];
#pragma unroll
    for (int u = 0; u < UW; ++u) F[u] = ph4[pbase + 2 * u];
#pragma unroll
    for (int jk = 0; jk < NK; ++jk) {
        const half8 aCur = __builtin_bit_cast(half8, Ap[aBase + jk * 64]);
#pragma unroll
        for (int u = 0; u < UW; ++u) {
            acc[u] = __builtin_amdgcn_mfma_f32_16x16x32_f16(
                aCur, __builtin_bit_cast(half8, F[(2 * jk + u) % UW]), acc[u], 0, 0, 0);
        }
        if (jk + 1 < NK) {
            F[(2 * jk) % UW]     = ph4[pbase + 4 * (jk + 1) + 16];
            F[(2 * jk + 1) % UW] = ph4[pbase + 4 * (jk + 1) + 18];
        }
    }
}

// ---------- kernel1: MFMA Gabor conv -> power P[b][f][t] (f16), ALL batches ----------
__global__ __launch_bounds__(256) void leaf_conv(
    const float* __restrict__ x,
    const float* __restrict__ sigma_g,
    const _Float16* __restrict__ Atab,
    _Float16* __restrict__ Pall)           // [8][40][160000] f16
{
    __shared__ unsigned ph[8 * PHS];       // 8 phase-shifted fragment arrays

    const int gi = blockIdx.x % NG;
    const int ch = (blockIdx.x / NG) % NCH1;
    const int b  = blockIdx.x / (NG * NCH1);
    const int f0 = gi * GF;
    const int tid = threadIdx.x;
    const int lane = tid & 63;
    const int w    = tid >> 6;

    const float* __restrict__ xb = x + (size_t)b * T_LEN;
    _Float16* __restrict__ Pb = Pall + (size_t)b * F_FILT * T_LEN;

    int klo, nk;
    group_span(sigma_g[f0], klo, nk);
    const int t0   = ch * TC;
    const int base = t0 + klo - 400;

    // ---- stage x: build all 8 phase-shifted 16B fragments per 8-sample slot ----
    if (tid < NSTG) {
        const int g0 = base + 8 * tid;
        float v[15];
        if (g0 >= 0 && g0 + 14 < T_LEN) {
            const float4 a0 = *(const float4*)(xb + g0);
            const float4 a1 = *(const float4*)(xb + g0 + 4);
            const float4 a2 = *(const float4*)(xb + g0 + 8);
            const float4 a3 = *(const float4*)(xb + g0 + 12);
            v[0]=a0.x; v[1]=a0.y; v[2]=a0.z; v[3]=a0.w;
            v[4]=a1.x; v[5]=a1.y; v[6]=a1.z; v[7]=a1.w;
            v[8]=a2.x; v[9]=a2.y; v[10]=a2.z; v[11]=a2.w;
            v[12]=a3.x; v[13]=a3.y; v[14]=a3.z;
        } else {
#pragma unroll
            for (int e = 0; e < 15; ++e) {
                const int gidx = g0 + e;
                v[e] = (gidx >= 0 && gidx < T_LEN) ? xb[gidx] : 0.f;
            }
        }
        unsigned pw[14];
#pragma unroll
        for (int s = 0; s < 14; ++s) pw[s] = pk2(v[s], v[s + 1]);
#pragma unroll
        for (int r = 0; r < 8; ++r) {
            uint4 fr;
            fr.x = pw[r]; fr.y = pw[r + 2]; fr.z = pw[r + 4]; fr.w = pw[r + 6];
            *(uint4*)&ph[r * PHS + 4 * tid] = fr;
        }
    }
    __syncthreads();

    // ---- k-loop: 10 j-tiles per wave, 1 b128 per fragment ----
    const int n  = lane & 15;
    const int kb = lane >> 4;
    const int q  = n + 8 * kb + 160 * w;       // fragment start sample offset
    const int pbase = (q & 7) * (PHS / 4) + (q >> 3);   // uint4 index; + 2u + 4jk

    f32x4 acc[UW];
#pragma unroll
    for (int u = 0; u < UW; ++u) acc[u] = (f32x4){0.f, 0.f, 0.f, 0.f};

    const uint4* ph4 = (const uint4*)ph;
    const uint4* Ap = (const uint4*)Atab;
    const int aBase = (gi * 52 + kb) * 16 + n;   // c8 = 4jk + kb

    switch (nk) {
        case 3:  conv_kloop<3>(ph4, Ap, aBase, pbase, acc); break;
        case 4:  conv_kloop<4>(ph4, Ap, aBase, pbase, acc); break;
        case 5:  conv_kloop<5>(ph4, Ap, aBase, pbase, acc); break;
        case 6:
        case 7:  conv_kloop<7>(ph4, Ap, aBase, pbase, acc); break;
        case 8:
        case 9:  conv_kloop<9>(ph4, Ap, aBase, pbase, acc); break;
        default: conv_kloop<13>(ph4, Ap, aBase, pbase, acc); break;
    }

    // ---- epilogue: power, store P ----
    const int g  = lane >> 4;
    const int fA = f0 + 2 * g;
#pragma unroll
    for (int u = 0; u < UW; ++u) {
        const int t = t0 + (w * UW + u) * 16 + n;
        const float P0 = acc[u].x * acc[u].x + acc[u].y * acc[u].y;
        const float P1 = acc[u].z * acc[u].z + acc[u].w * acc[u].w;
        Pb[(size_t)fA * T_LEN + t]       = (_Float16)P0;
        Pb[(size_t)(fA + 1) * T_LEN + t] = (_Float16)P1;
    }
}

// ---------- kernel2: EMA + PCEN + pooling, barrier-free (one wave = one span) ----------
__global__ __launch_bounds__(PC_THREADS) void leaf_pcen(
    const _Float16* __restrict__ Pall,
    const float* __restrict__ bias_g,
    const float* __restrict__ ema_g,
    const float* __restrict__ alpha_g,
    const float* __restrict__ delta_g,
    const float* __restrict__ root_g,
    const unsigned* __restrict__ pktab,
    float* __restrict__ outp)
{
    __shared__ unsigned lds[PC_NWAVES * WSTR];

    const int tid  = threadIdx.x;
    const int lane = tid & 63;
    const int wv   = tid >> 6;
    const int wid  = blockIdx.x * PC_NWAVES + wv;   // 0..7999
    const int sp   = wid % NSP;
    const int bf   = wid / NSP;
    const int f    = bf % F_FILT;

    unsigned* ring = lds + wv * WSTR;        // [0,200) halo | [200,840) tile
    unsigned* pkl  = ring + RINGW;           // pool kernel, 208 words

    const float sw    = fminf(fmaxf(ema_g[f], 0.0f), 1.0f);
    const float a     = 1.0f - sw;
    const float alpha = fminf(alpha_g[f], 1.0f);
    const float inv_r = 1.0f / fmaxf(root_g[f], 1.0f);
    const float dlt   = delta_g[f];
    const float dpow  = fexp2(inv_r * flog2(dlt));
    const bool  rt1   = (inv_r == 1.0f);     // (q+d)^1 - d^1 == p*denp
    const float bias  = bias_g[f];

    for (int i = lane; i < KP; i += 64) pkl[i] = pktab[f * KP + i];
    for (int i = lane; i < HALOP; i += 64) ring[i] = 0u;

    // scan factors: A1 = a^RT (a^20); A64 = per-tile decay a^1280
    const float a2 = a * a, a4 = a2 * a2, a8 = a4 * a4, a16 = a8 * a8;
    const float A1  = a16 * a4;          // a^20
    const float A2  = A1 * A1, A4 = A2 * A2, A8 = A4 * A4;
    const float A16 = A8 * A8, A32 = A16 * A16, A64 = A32 * A32;
    float Al = 1.0f;
    if (lane & 1)  Al *= A1;
    if (lane & 2)  Al *= A2;
    if (lane & 4)  Al *= A4;
    if (lane & 8)  Al *= A8;
    if (lane & 16) Al *= A16;
    if (lane & 32) Al *= A32;

    const unsigned* PU = (const unsigned*)(Pall + (size_t)bf * T_LEN);
    const int wbase = sp * (SPAN / 2);       // word base of this span
    const int itStart = (sp == 0) ? 0 : -1;  // warm-up tile for sp>0
    float carry = 0.f;

    unsigned sv[10];
    {
        const int tb = wbase + itStart * 640 + lane * 10;
#pragma unroll
        for (int q = 0; q < 10; ++q) sv[q] = PU[tb + q];
    }

    for (int it = itStart; it < W_NT; ++it) {
        // unpack powers
        float p[RT];
#pragma unroll
        for (int q = 0; q < 10; ++q) {
            const h2_t hh = bch(sv[q]);
            p[2 * q]     = (float)hh.x;
            p[2 * q + 1] = (float)hh.y;
        }
        // prefetch next tile
        {
            const int nt = it + 1;
            const int tb = wbase + (nt < W_NT ? nt : 0) * 640 + lane * 10;
#pragma unroll
            for (int q = 0; q < 10; ++q) sv[q] = PU[tb + q];
        }

        float up[RT];
        float uu = 0.f;
#pragma unroll
        for (int r = 0; r < RT; ++r) {
            uu = fmaf(a, uu, sw * p[r]);
            up[r] = uu;
        }

        float cc = carry;
        if (sp == 0 && it == 0) cc = __shfl(p[0], 0);   // ema[0] = p[0] (a+sw=1)

        // intra-wave Kogge-Stone scan
        float v = uu;
        {
            float tv;
            tv = __shfl_up(v, 1);  if (lane >= 1)  v = fmaf(A1,  tv, v);
            tv = __shfl_up(v, 2);  if (lane >= 2)  v = fmaf(A2,  tv, v);
            tv = __shfl_up(v, 4);  if (lane >= 4)  v = fmaf(A4,  tv, v);
            tv = __shfl_up(v, 8);  if (lane >= 8)  v = fmaf(A8,  tv, v);
            tv = __shfl_up(v, 16); if (lane >= 16) v = fmaf(A16, tv, v);
            tv = __shfl_up(v, 32); if (lane >= 32) v = fmaf(A32, tv, v);
        }
        const float vlast = __shfl(v, 63);
        float cin;
        {
            float ve = __shfl_up(v, 1);
            if (lane == 0) ve = 0.f;
            cin = fmaf(Al, cc, ve);
        }
        carry = fmaf(A64, cc, vlast);

        // PCEN + f16 ring writes (own wave region only)
        float apr = a;
#pragma unroll
        for (int j = 0; j < 10; ++j) {
            const float e0 = fmaf(apr, cin, up[2 * j]);     apr *= a;
            const float e1 = fmaf(apr, cin, up[2 * j + 1]); apr *= a;
            const float d0 = fexp2(-alpha * flog2(EPS_PCENF + e0));
            const float d1 = fexp2(-alpha * flog2(EPS_PCENF + e1));
            float c0, c1;
            if (rt1) {
                c0 = p[2 * j] * d0;
                c1 = p[2 * j + 1] * d1;
            } else {
                const float q0 = fmaf(p[2 * j],     d0, dlt);
                const float q1 = fmaf(p[2 * j + 1], d1, dlt);
                c0 = fexp2(inv_r * flog2(q0)) - dpow;
                c1 = fexp2(inv_r * flog2(q1)) - dpow;
            }
            ring[HALOP + lane * 10 + j] = pk2(c0, c1);
        }

        // pooling: 8 outputs x 8 lanes, direct global write
        if (it >= 0) {
            const int o = lane >> 3, l = lane & 7;
            float part = 0.f;
#pragma unroll
            for (int t = 0; t < 26; ++t) {
                const int kpp = l + 8 * t;    // 0..207
                part = fdot2(bch(ring[o * 80 + kpp]), bch(pkl[kpp]), part);
            }
            part += __shfl_xor(part, 1, 8);
            part += __shfl_xor(part, 2, 8);
            part += __shfl_xor(part, 4, 8);
            if (l == 0)
                outp[(size_t)bf * 1000 + sp * (W_NT * 8) + it * 8 + o] = part + bias;
        }

        // slide halo: 200 words = 50 uint4 (read [640,840) -> write [0,200))
        if (lane < 50) {
            const uint4 hv = *(const uint4*)&ring[640 + 4 * lane];
            *(uint4*)&ring[4 * lane] = hv;
        }
    }
}

// ---------- instance norm over 1000 frames, in place ----------
__global__ __launch_bounds__(256) void leaf_norm(float* __restrict__ out)
{
    const int bf = blockIdx.x;
    float* p = out + (size_t)bf * 1000;
    __shared__ float buf[1000];
    __shared__ float red[4];
    const int tid = threadIdx.x;
    const int lane = tid & 63, wave = tid >> 6;

    float sum = 0.0f;
    for (int i = tid; i < 1000; i += 256) { float v = p[i]; buf[i] = v; sum += v; }
    for (int m = 1; m < 64; m <<= 1) sum += __shfl_xor(sum, m);
    if (lane == 0) red[wave] = sum;
    __syncthreads();
    const float mean = (red[0] + red[1] + red[2] + red[3]) * 0.001f;

    float vs = 0.0f;
    for (int i = tid; i < 1000; i += 256) { float d = buf[i] - mean; vs += d * d; }
    for (int m = 1; m < 64; m <<= 1) vs += __shfl_xor(vs, m);
    __syncthreads();
    if (lane == 0) red[wave] = vs;
    __syncthreads();
    const float var   = (red[0] + red[1] + red[2] + red[3]) * 0.001f;
    const float scale = rsqrtf(var + EPS_INF);
    for (int i = tid; i < 1000; i += 256) p[i] = (buf[i] - mean) * scale;
}

extern "C" void kernel_launch(void* const* d_in, const int* in_sizes, int n_in,
                              void* d_out, int out_size, void* d_ws, size_t ws_size,
                              hipStream_t stream)
{
    const float* x     = (const float*)d_in[0];
    const float* eta   = (const float*)d_in[1];
    const float* sigma = (const float*)d_in[2];
    const float* bw    = (const float*)d_in[3];
    const float* bias  = (const float*)d_in[4];
    const float* emaw  = (const float*)d_in[5];
    const float* alpha = (const float*)d_in[6];
    const float* delta = (const float*)d_in[7];
    const float* root  = (const float*)d_in[8];
    float* outp = (float*)d_out;

    _Float16* Atab  = (_Float16*)d_ws;                       // 133,120 B
    unsigned* pktab = (unsigned*)((char*)d_ws + 133120);     // 33,280 B
    _Float16* Pall  = (_Float16*)((char*)d_ws + 166400);     // 8*40*160000*2 = 102.4 MB

    hipLaunchKernelGGL(leaf_weights, dim3(NG), dim3(256), 0, stream,
                       eta, sigma, bw, Atab, pktab);
    hipLaunchKernelGGL(leaf_conv, dim3(B_BATCH * NG * NCH1), dim3(256), 0, stream,
                       x, sigma, Atab, Pall);
    hipLaunchKernelGGL(leaf_pcen, dim3(B_BATCH * F_FILT * NSP / PC_NWAVES), dim3(PC_THREADS),
                       0, stream, Pall, bias, emaw, alpha, delta, root, pktab, outp);
    hipLaunchKernelGGL(leaf_norm, dim3(B_BATCH * F_FILT), dim3(256), 0, stream, outp);
}